// Round 13
// baseline (106.204 us; speedup 1.0000x reference)
//
#include <hip/hip_runtime.h>
#include <hip/hip_bf16.h>

typedef __attribute__((ext_vector_type(4))) float f32x4;
typedef __attribute__((ext_vector_type(8))) short short8;
typedef __attribute__((ext_vector_type(4))) unsigned int u32x4;

#define ALPHA 0.2f
#define NEG_BIG -9e15f

static __device__ __forceinline__ short f2bf(float f) {
    __hip_bfloat16 b = __float2bfloat16(f);
    return __builtin_bit_cast(short, b);
}

#define MFMA16(A, B, C) __builtin_amdgcn_mfma_f32_16x16x32_bf16((A), (B), (C), 0, 0, 0)

// ---------------------------------------------------------------------------
// K00: ws = W @ a_src, wd = W @ a_dst  (128-vectors, exact f32)
__global__ __launch_bounds__(128) void k00_wsd(const float* __restrict__ W,
                                               const float* __restrict__ a,
                                               float* __restrict__ wsv,
                                               float* __restrict__ wdv) {
    int k = blockIdx.x, t = threadIdx.x;
    float v = W[k * 128 + t];
    float ps = v * a[t];
    float pd = v * a[128 + t];
    #pragma unroll
    for (int d = 1; d < 64; d <<= 1) {
        ps += __shfl_xor(ps, d);
        pd += __shfl_xor(pd, d);
    }
    __shared__ float tmp[4];
    if ((t & 63) == 0) { tmp[(t >> 6) * 2] = ps; tmp[(t >> 6) * 2 + 1] = pd; }
    __syncthreads();
    if (t == 0) { wsv[k] = tmp[0] + tmp[2]; wdv[k] = tmp[1] + tmp[3]; }
}

// ---------------------------------------------------------------------------
// K0: Wh = h@W via bf16 MFMA -> store transposed bf16 Whbt[m][o][node];
//     also es/ed exact f32. NT: h loads, whbt stores (protect adj L3 space).
__global__ __launch_bounds__(256) void k0_wh(const float* __restrict__ h,
                                             const float* __restrict__ W,
                                             const float* __restrict__ wsv,
                                             const float* __restrict__ wdv,
                                             short* __restrict__ whbt,
                                             float* __restrict__ es,
                                             float* __restrict__ ed) {
    __shared__ __align__(16) short Wt[128 * 136];
    __shared__ __align__(16) float lws[128], lwd[128];
    const int tid = threadIdx.x;
    const int m = blockIdx.x >> 3, rt = blockIdx.x & 7;
    const int R0 = rt * 128;
    #pragma unroll 4
    for (int i = 0; i < 64; ++i) {
        int idx = i * 256 + tid;
        int k = idx >> 7, o = idx & 127;
        Wt[o * 136 + k] = f2bf(W[idx]);
    }
    if (tid < 128) { lws[tid] = wsv[tid]; lwd[tid] = wdv[tid]; }
    __syncthreads();
    const int w = tid >> 6, l = tid & 63;
    const int q = l >> 4, c = l & 15;
    const int row0 = R0 + w * 32 + c;
    f32x4 acc[2][8];
    const f32x4 vzero = {0.f, 0.f, 0.f, 0.f};
    #pragma unroll
    for (int i = 0; i < 2; ++i)
        #pragma unroll
        for (int j = 0; j < 8; ++j) acc[i][j] = vzero;
    float esp0 = 0.f, edp0 = 0.f, esp1 = 0.f, edp1 = 0.f;
    const float* hrow0 = h + ((size_t)m * 1024 + row0) * 128;
    const float* hrow1 = hrow0 + 16 * 128;
    #pragma unroll
    for (int kk = 0; kk < 128; kk += 32) {
        const int kb = kk + q * 8;
        f32x4 wsA = *(const f32x4*)&lws[kb], wsB = *(const f32x4*)&lws[kb + 4];
        f32x4 wdA = *(const f32x4*)&lwd[kb], wdB = *(const f32x4*)&lwd[kb + 4];
        f32x4 h0a = __builtin_nontemporal_load((const f32x4*)(hrow0 + kb));
        f32x4 h0b = __builtin_nontemporal_load((const f32x4*)(hrow0 + kb + 4));
        f32x4 h1a = __builtin_nontemporal_load((const f32x4*)(hrow1 + kb));
        f32x4 h1b = __builtin_nontemporal_load((const f32x4*)(hrow1 + kb + 4));
        short8 af0, af1;
        #pragma unroll
        for (int e = 0; e < 4; ++e) {
            esp0 += h0a[e] * wsA[e] + h0b[e] * wsB[e];
            edp0 += h0a[e] * wdA[e] + h0b[e] * wdB[e];
            esp1 += h1a[e] * wsA[e] + h1b[e] * wsB[e];
            edp1 += h1a[e] * wdA[e] + h1b[e] * wdB[e];
            af0[e] = f2bf(h0a[e]); af0[e + 4] = f2bf(h0b[e]);
            af1[e] = f2bf(h1a[e]); af1[e + 4] = f2bf(h1b[e]);
        }
        #pragma unroll
        for (int nf = 0; nf < 8; ++nf) {
            short8 bf = *(const short8*)&Wt[(nf * 16 + c) * 136 + kb];
            acc[0][nf] = MFMA16(af0, bf, acc[0][nf]);
            acc[1][nf] = MFMA16(af1, bf, acc[1][nf]);
        }
    }
    {
        float v0 = esp0; v0 += __shfl_xor(v0, 16); v0 += __shfl_xor(v0, 32);
        float u0 = edp0; u0 += __shfl_xor(u0, 16); u0 += __shfl_xor(u0, 32);
        float v1 = esp1; v1 += __shfl_xor(v1, 16); v1 += __shfl_xor(v1, 32);
        float u1 = edp1; u1 += __shfl_xor(u1, 16); u1 += __shfl_xor(u1, 32);
        if (q == 0) {
            es[m * 1024 + row0] = v0;       ed[m * 1024 + row0] = u0;
            es[m * 1024 + row0 + 16] = v1;  ed[m * 1024 + row0 + 16] = u1;
        }
    }
    #pragma unroll
    for (int mf = 0; mf < 2; ++mf) {
        const int rowb = R0 + w * 32 + mf * 16 + q * 4;
        #pragma unroll
        for (int nf = 0; nf < 8; ++nf) {
            const int o = nf * 16 + c;
            size_t base = ((size_t)m * 128 + o) * 1024 + rowb;
            #pragma unroll
            for (int r = 0; r < 4; r += 2) {
                unsigned lo = (unsigned short)f2bf(acc[mf][nf][r]);
                unsigned hi = (unsigned short)f2bf(acc[mf][nf][r + 1]);
                __builtin_nontemporal_store(lo | (hi << 16), (unsigned*)(whbt + base + r));
            }
        }
    }
}

// ---------------------------------------------------------------------------
// K0m: Mall[m] = max_i es[m][i]
__global__ __launch_bounds__(256) void k0m_max(const float* __restrict__ es,
                                               float* __restrict__ mall) {
    const int m = blockIdx.x, tid = threadIdx.x;
    float4 v = *(const float4*)&es[m * 1024 + tid * 4];
    float mx = fmaxf(fmaxf(v.x, v.y), fmaxf(v.z, v.w));
    #pragma unroll
    for (int d = 1; d < 64; d <<= 1) mx = fmaxf(mx, __shfl_xor(mx, d));
    __shared__ float t[4];
    if ((tid & 63) == 0) t[tid >> 6] = mx;
    __syncthreads();
    if (tid == 0) mall[m] = fmaxf(fmaxf(t[0], t[1]), fmaxf(t[2], t[3]));
}

// ---------------------------------------------------------------------------
// K1 (R3's three-phase): adj loads CACHEABLE (we want L3 retention across
// replays). Phase L: 16 independent int4 loads; Phase B: ballots+bit stores;
// Phase M: exp/sum math.
// grid 32*64 (m, 16-row chunk), block 256 (thread = 4 columns).
// Bit layout: word jw = (j>>8)*4 + (j&3), bit (j>>2)&63.
__global__ __launch_bounds__(256) void k1_stats(const int* __restrict__ adj,
                                                const float* __restrict__ es,
                                                const float* __restrict__ ed,
                                                const float* __restrict__ mall,
                                                unsigned long long* __restrict__ bits,
                                                float* __restrict__ spart) {
    const int b = blockIdx.x;
    const int m = b >> 6, it = b & 63;
    const int tid = threadIdx.x;
    const int w = tid >> 6, l = tid & 63;
    const int j0 = tid * 4;
    const float Ma = mall[m];
    const float4 edv = *(const float4*)&ed[m * 1024 + j0];
    float ub[4];
    #pragma unroll
    for (int e = 0; e < 4; ++e) {
        float x = Ma + ((const float*)&edv)[e];
        ub[e] = fmaxf(x, ALPHA * x);
    }
    const int4* ap = (const int4*)(adj + ((size_t)m * 1024 + it * 16) * 1024) + tid;
    int4 av[16];
    #pragma unroll
    for (int r = 0; r < 16; ++r) av[r] = ap[(size_t)r * 256];
    __builtin_amdgcn_sched_barrier(0);
    unsigned long long* bp = bits + ((size_t)m * 1024 + it * 16) * 16 + w * 4;
    #pragma unroll
    for (int r = 0; r < 16; ++r) {
        unsigned long long b0 = __ballot(av[r].x != 0);
        unsigned long long b1 = __ballot(av[r].y != 0);
        unsigned long long b2 = __ballot(av[r].z != 0);
        unsigned long long b3 = __ballot(av[r].w != 0);
        if (l == 0) {
            ulonglong2 p0, p1;
            p0.x = b0; p0.y = b1; p1.x = b2; p1.y = b3;
            *(ulonglong2*)(bp + (size_t)r * 16) = p0;
            *(ulonglong2*)(bp + (size_t)r * 16 + 2) = p1;
        }
    }
    float sr[4] = {0.f, 0.f, 0.f, 0.f};
    const float* ep = es + m * 1024 + it * 16;
    #pragma unroll
    for (int r = 0; r < 16; ++r) {
        const float esb = ep[r];
        #pragma unroll
        for (int e = 0; e < 4; ++e) {
            float x = esb + ((const float*)&edv)[e];
            float lk = fmaxf(x, ALPHA * x);
            float t = __expf(lk - ub[e]);
            sr[e] += ((&av[r].x)[e] != 0) ? t : 0.f;
        }
    }
    float4 s4; s4.x = sr[0]; s4.y = sr[1]; s4.z = sr[2]; s4.w = sr[3];
    *(float4*)&spart[((size_t)(m * 64 + it)) * 1024 + j0] = s4;
}

// ---------------------------------------------------------------------------
// K1b: sum the 64 i-chunk partials -> cc, dinv.
__global__ __launch_bounds__(256) void k1b_combine(const float* __restrict__ spart,
                                                   const float* __restrict__ ed,
                                                   const float* __restrict__ mall,
                                                   float* __restrict__ cc,
                                                   float* __restrict__ dinv) {
    const int g = blockIdx.x * 256 + threadIdx.x;   // 32*1024
    const int m = g >> 10, j = g & 1023;
    const float* sp = spart + (size_t)m * 64 * 1024 + j;
    float S = 0.f;
    #pragma unroll
    for (int it = 0; it < 64; ++it) S += sp[it * 1024];
    float x = mall[m] + ed[g];
    float ub = fmaxf(x, ALPHA * x);
    bool dead = !(S > 0.f);                          // all-masked column
    cc[g] = dead ? NEG_BIG : ub;
    dinv[g] = dead ? (1.0f / 1024.0f) : 1.0f / S;
}

// ---------------------------------------------------------------------------
// K2: fused  out = elu( P @ Whb ). NT: whbt loads, out stores.
__global__ __launch_bounds__(256) void k2_pv(const unsigned long long* __restrict__ bits,
                                             const short* __restrict__ whbt,
                                             const float* __restrict__ es,
                                             const float* __restrict__ ed,
                                             const float* __restrict__ cc,
                                             const float* __restrict__ dinv,
                                             float* __restrict__ out) {
    __shared__ __align__(16) short Bt[2][128 * 40];
    __shared__ __align__(16) float led[1024], lc[1024], ld[1024];
    const int tid = threadIdx.x;
    const int m = blockIdx.x >> 3, rt = blockIdx.x & 7;
    const int R0 = rt * 128;
    for (int i = tid; i < 1024; i += 256) {
        led[i] = ed[m * 1024 + i];
        lc[i] = cc[m * 1024 + i];
        ld[i] = dinv[m * 1024 + i];
    }
    const int w = tid >> 6, l = tid & 63, q = l >> 4, cl = l & 15;
    const int row0 = R0 + w * 32 + cl;
    const float es0 = es[m * 1024 + row0];
    const float es1 = es[m * 1024 + row0 + 16];
    const unsigned long long* bp0 = bits + ((size_t)m * 1024 + row0) * 16;
    const unsigned long long* bp1 = bp0 + 16 * 16;
    f32x4 acc[2][8];
    const f32x4 vzero = {0.f, 0.f, 0.f, 0.f};
    #pragma unroll
    for (int i = 0; i < 2; ++i)
        #pragma unroll
        for (int jx = 0; jx < 8; ++jx) acc[i][jx] = vzero;
    const int so = tid >> 1, sh = tid & 1;
    const short* gsrc = whbt + ((size_t)m * 128 + so) * 1024 + sh * 16;
    short* dst0 = &Bt[0][so * 40 + sh * 16];
    {
        u32x4 r0 = __builtin_nontemporal_load((const u32x4*)gsrc);
        u32x4 r1 = __builtin_nontemporal_load((const u32x4*)(gsrc + 8));
        *(u32x4*)dst0 = r0;
        *(u32x4*)(dst0 + 8) = r1;
    }
    __syncthreads();
    int cur = 0;
    ulonglong2 wa0, wb0, wa1, wb1;
    wa0.x = wa0.y = wb0.x = wb0.y = 0ull;
    wa1.x = wa1.y = wb1.x = wb1.y = 0ull;
    #pragma unroll 2
    for (int kt = 0; kt < 32; ++kt) {
        const int jb = kt * 32 + q * 8;
        if ((kt & 7) == 0) {
            const ulonglong2* q0 = (const ulonglong2*)(bp0 + (kt >> 3) * 4);
            wa0 = q0[0]; wb0 = q0[1];
            const ulonglong2* q1 = (const ulonglong2*)(bp1 + (kt >> 3) * 4);
            wa1 = q1[0]; wb1 = q1[1];
        }
        u32x4 n0, n1;
        if (kt < 31) {
            const short* g2 = gsrc + (kt + 1) * 32;
            n0 = __builtin_nontemporal_load((const u32x4*)g2);
            n1 = __builtin_nontemporal_load((const u32x4*)(g2 + 8));
        }
        const f32x4 edA = *(const f32x4*)&led[jb], edB = *(const f32x4*)&led[jb + 4];
        const f32x4 cA = *(const f32x4*)&lc[jb],   cB = *(const f32x4*)&lc[jb + 4];
        const f32x4 dA = *(const f32x4*)&ld[jb],   dB = *(const f32x4*)&ld[jb + 4];
        const int bbase = ((kt & 7) << 3) + (q << 1);
        short8 af0, af1;
        #pragma unroll
        for (int e = 0; e < 8; ++e) {
            const float edv = (e < 4) ? edA[e] : edB[e - 4];
            const float cv = (e < 4) ? cA[e] : cB[e - 4];
            const float dv = (e < 4) ? dA[e] : dB[e - 4];
            const float x0 = es0 + edv, x1 = es1 + edv;
            const float l0 = fmaxf(x0, ALPHA * x0), l1 = fmaxf(x1, ALPHA * x1);
            const int bi = bbase + (e >> 2);
            const unsigned long long q0w = (e & 3) == 0 ? wa0.x : (e & 3) == 1 ? wa0.y
                                         : (e & 3) == 2 ? wb0.x : wb0.y;
            const unsigned long long q1w = (e & 3) == 0 ? wa1.x : (e & 3) == 1 ? wa1.y
                                         : (e & 3) == 2 ? wb1.x : wb1.y;
            const float m0 = ((q0w >> bi) & 1ull) ? l0 : NEG_BIG;
            const float m1 = ((q1w >> bi) & 1ull) ? l1 : NEG_BIG;
            af0[e] = f2bf(__expf(m0 - cv) * dv);
            af1[e] = f2bf(__expf(m1 - cv) * dv);
        }
        const short* bb = &Bt[cur][0];
        #pragma unroll
        for (int nf = 0; nf < 8; ++nf) {
            short8 bf = *(const short8*)&bb[(nf * 16 + cl) * 40 + q * 8];
            acc[0][nf] = MFMA16(af0, bf, acc[0][nf]);
            acc[1][nf] = MFMA16(af1, bf, acc[1][nf]);
        }
        if (kt < 31) {
            short* d2 = &Bt[cur ^ 1][so * 40 + sh * 16];
            *(u32x4*)d2 = n0;
            *(u32x4*)(d2 + 8) = n1;
            cur ^= 1;
        }
        __syncthreads();
    }
    #pragma unroll
    for (int mf = 0; mf < 2; ++mf) {
        const int rowb = R0 + w * 32 + mf * 16 + q * 4;
        #pragma unroll
        for (int nf = 0; nf < 8; ++nf) {
            const int o = nf * 16 + cl;
            #pragma unroll
            for (int r = 0; r < 4; ++r) {
                const float v = acc[mf][nf][r];
                const float evv = v > 0.f ? v : (__expf(v) - 1.0f);
                __builtin_nontemporal_store(evv, out + ((size_t)m * 1024 + rowb + r) * 128 + o);
            }
        }
    }
}

// ---------------------------------------------------------------------------
extern "C" void kernel_launch(void* const* d_in, const int* in_sizes, int n_in,
                              void* d_out, int out_size, void* d_ws, size_t ws_size,
                              hipStream_t stream) {
    const float* h = (const float*)d_in[0];
    const int* adj = (const int*)d_in[1];
    const float* W = (const float*)d_in[2];
    const float* a = (const float*)d_in[3];
    float* out = (float*)d_out;

    char* p = (char*)d_ws;
    auto alloc = [&](size_t bytes) -> char* {
        char* r = p;
        p += (bytes + 255) & ~(size_t)255;
        return r;
    };
    short* whbt = (short*)alloc((size_t)32 * 128 * 1024 * 2);                          // 8 MB
    float* es = (float*)alloc((size_t)32 * 1024 * 4);
    float* ed = (float*)alloc((size_t)32 * 1024 * 4);
    float* wsv = (float*)alloc(128 * 4);
    float* wdv = (float*)alloc(128 * 4);
    float* mall = (float*)alloc(32 * 4);
    unsigned long long* bits = (unsigned long long*)alloc((size_t)32 * 1024 * 16 * 8); // 4 MB
    float* spart = (float*)alloc((size_t)32 * 64 * 1024 * 4);                          // 8 MB
    float* cc = (float*)alloc((size_t)32 * 1024 * 4);
    float* dinv = (float*)alloc((size_t)32 * 1024 * 4);

    k00_wsd<<<128, 128, 0, stream>>>(W, a, wsv, wdv);
    k0_wh<<<256, 256, 0, stream>>>(h, W, wsv, wdv, whbt, es, ed);
    k0m_max<<<32, 256, 0, stream>>>(es, mall);
    k1_stats<<<2048, 256, 0, stream>>>(adj, es, ed, mall, bits, spart);
    k1b_combine<<<128, 256, 0, stream>>>(spart, ed, mall, cc, dinv);
    k2_pv<<<256, 256, 0, stream>>>(bits, whbt, es, ed, cc, dinv, out);
}

// Round 14
// 88.828 us; speedup vs baseline: 1.1956x; 1.1956x over previous
//
#include <hip/hip_runtime.h>
#include <hip/hip_bf16.h>
#include <hip/hip_cooperative_groups.h>

namespace cg = cooperative_groups;

typedef __attribute__((ext_vector_type(4))) float f32x4;
typedef __attribute__((ext_vector_type(8))) short short8;
typedef __attribute__((ext_vector_type(4))) int i32x4;

#define ALPHA 0.2f
#define NEG_BIG -9e15f
#define WTP 138   // W^T LDS pad (shorts): bank = (5*cl+4*q)%32 -> <=2-way

static __device__ __forceinline__ short f2bf(float f) {
    __hip_bfloat16 b = __float2bfloat16(f);
    return __builtin_bit_cast(short, b);
}

#define MFMA16(A, B, C) __builtin_amdgcn_mfma_f32_16x16x32_bf16((A), (B), (C), 0, 0, 0)

// ---------------------------------------------------------------------------
// LDS overlays; max(SA,SB,SC) = SA = 37376 B -> 2 blocks/CU (74.8KB < 160KB)
struct SA { short Wt[128 * WTP]; float la[256]; float lws[128]; float lwd[128]; };
struct SB { int buf[2][4096]; float les[64]; float red[8]; };
struct SC { short Bt[2][128 * 40]; float led[1024]; float lc[1024]; float ld[1024]; float red[8]; };

// ===========================================================================
// MEGA v2: cooperative, grid 512 (2 blocks/CU), 2 grid syncs.
// Block b -> m = b>>4, sub = b&15; each phase handles 64 rows T0=sub*64.
// Roofline note (R14): adj first-touch read is latency*concurrency-capped at
// ~1.9 TB/s on this chip (external ref: rocclr copyBuffer reads 1.4 TB/s);
// 134 MB / 1.9 TB/s ~= 71 us + ~15 us compute phases = the observed ~89 us.
// ===========================================================================
__global__ __launch_bounds__(256) void gat_mega(
        const float* __restrict__ h, const int* __restrict__ adj,
        const float* __restrict__ W, const float* __restrict__ a,
        short* __restrict__ whbt, float* __restrict__ es, float* __restrict__ ed,
        unsigned long long* __restrict__ bits, float* __restrict__ spart,
        float* __restrict__ out) {
    __shared__ __align__(16) char smem[37632];
    cg::grid_group grid = cg::this_grid();
    const int b = blockIdx.x;
    const int tid = threadIdx.x;
    const int w = tid >> 6, l = tid & 63;
    const int q = l >> 4, cl = l & 15;
    const int m = b >> 4, sub = b & 15;
    const int T0 = sub * 64;

    // ========== PHASE A: ws/wd + Wh GEMM (64 rows) + es/ed =================
    {
        SA* S = (SA*)smem;
        S->la[tid] = a[tid];
        __syncthreads();
        {   // exact f32 ws/wd, duplicated per block
            const int k = tid >> 1, hh = tid & 1;
            const float* wr = W + k * 128 + hh * 64;
            float ps = 0.f, pd = 0.f;
            #pragma unroll
            for (int f = 0; f < 64; f += 4) {
                f32x4 wv = *(const f32x4*)(wr + f);
                #pragma unroll
                for (int e = 0; e < 4; ++e) {
                    ps += wv[e] * S->la[hh * 64 + f + e];
                    pd += wv[e] * S->la[128 + hh * 64 + f + e];
                }
            }
            ps += __shfl_xor(ps, 1);
            pd += __shfl_xor(pd, 1);
            if (hh == 0) { S->lws[k] = ps; S->lwd[k] = pd; }
        }
        #pragma unroll 4
        for (int i = 0; i < 64; ++i) {
            int idx = i * 256 + tid;
            int kk = idx >> 7, o = idx & 127;
            S->Wt[o * WTP + kk] = f2bf(W[idx]);
        }
        __syncthreads();
        const int row0 = T0 + w * 16 + cl;              // 16 rows per wave
        f32x4 acc[8];
        const f32x4 vz = {0.f, 0.f, 0.f, 0.f};
        #pragma unroll
        for (int j = 0; j < 8; ++j) acc[j] = vz;
        float esp0 = 0.f, edp0 = 0.f;
        const float* hrow0 = h + ((size_t)m * 1024 + row0) * 128;
        #pragma unroll
        for (int kk = 0; kk < 128; kk += 32) {
            const int kb = kk + q * 8;
            f32x4 wsA = *(const f32x4*)&S->lws[kb], wsB = *(const f32x4*)&S->lws[kb + 4];
            f32x4 wdA = *(const f32x4*)&S->lwd[kb], wdB = *(const f32x4*)&S->lwd[kb + 4];
            f32x4 h0a = *(const f32x4*)(hrow0 + kb), h0b = *(const f32x4*)(hrow0 + kb + 4);
            short8 af0;
            #pragma unroll
            for (int e = 0; e < 4; ++e) {
                esp0 += h0a[e] * wsA[e] + h0b[e] * wsB[e];
                edp0 += h0a[e] * wdA[e] + h0b[e] * wdB[e];
                af0[e] = f2bf(h0a[e]); af0[e + 4] = f2bf(h0b[e]);
            }
            #pragma unroll
            for (int nf = 0; nf < 8; ++nf) {
                short8 bf = *(const short8*)&S->Wt[(nf * 16 + cl) * WTP + kb];
                acc[nf] = MFMA16(af0, bf, acc[nf]);
            }
        }
        {
            float v0 = esp0; v0 += __shfl_xor(v0, 16); v0 += __shfl_xor(v0, 32);
            float u0 = edp0; u0 += __shfl_xor(u0, 16); u0 += __shfl_xor(u0, 32);
            if (q == 0) {
                es[m * 1024 + row0] = v0;
                ed[m * 1024 + row0] = u0;
            }
        }
        {
            const int rowb = T0 + w * 16 + q * 4;
            #pragma unroll
            for (int nf = 0; nf < 8; ++nf) {
                const int o = nf * 16 + cl;
                size_t base = ((size_t)m * 128 + o) * 1024 + rowb;
                #pragma unroll
                for (int r = 0; r < 4; r += 2) {
                    unsigned lo = (unsigned short)f2bf(acc[nf][r]);
                    unsigned hi = (unsigned short)f2bf(acc[nf][r + 1]);
                    *(unsigned*)(whbt + base + r) = lo | (hi << 16);
                }
            }
        }
    }
    __threadfence();
    grid.sync();

    // ========== PHASE B: adj DMA bitpack + column denominators =============
    {
        SB* S = (SB*)smem;
        {   // Mall for this m, in-block
            f32x4 ev = *(const f32x4*)&es[m * 1024 + tid * 4];
            float mx = fmaxf(fmaxf(ev[0], ev[1]), fmaxf(ev[2], ev[3]));
            #pragma unroll
            for (int d = 1; d < 64; d <<= 1) mx = fmaxf(mx, __shfl_xor(mx, d));
            if (l == 0) S->red[w] = mx;
        }
        const size_t gr2 = (size_t)m * 1024 + T0;
        if (tid < 64) S->les[tid] = es[gr2 + tid];
        __syncthreads();
        const float Ma = fmaxf(fmaxf(S->red[0], S->red[1]), fmaxf(S->red[2], S->red[3]));
        const int j0 = tid * 4;
        const f32x4 edv = *(const f32x4*)&ed[m * 1024 + j0];
        float ub[4], sr[4] = {0.f, 0.f, 0.f, 0.f};
        #pragma unroll
        for (int e = 0; e < 4; ++e) {
            float x = Ma + edv[e];
            ub[e] = fmaxf(x, ALPHA * x);
        }
        auto issue = [&](int s) {
            const int row = s * 4 + w;
            const int* gp = adj + (gr2 + row) * 1024 + l * 4;
            int* dst = &S->buf[s & 1][w * 1024];
            #pragma unroll
            for (int k = 0; k < 4; ++k)
                __builtin_amdgcn_global_load_lds(
                    (const __attribute__((address_space(1))) void*)(gp + k * 256),
                    (__attribute__((address_space(3))) void*)(dst + k * 256), 16, 0, 0);
        };
        issue(0);
        #pragma unroll 1
        for (int s = 0; s < 16; ++s) {
            if (s < 15) {
                issue(s + 1);
                // wave's own 4 newest (tile s+1) stay in flight; tile s drained.
                asm volatile("s_waitcnt vmcnt(4)" ::: "memory");
            } else {
                asm volatile("s_waitcnt vmcnt(0)" ::: "memory");
            }
            __builtin_amdgcn_s_barrier();   // every wave drained its tile-s DMA
            const int* bufc = S->buf[s & 1];
            unsigned long long* bprow = bits + (gr2 + (size_t)s * 4) * 16 + w * 4;
            #pragma unroll
            for (int r = 0; r < 4; ++r) {
                const i32x4 av = *(const i32x4*)&bufc[r * 1024 + j0];
                unsigned long long b0 = __ballot(av[0] != 0);
                unsigned long long b1 = __ballot(av[1] != 0);
                unsigned long long b2 = __ballot(av[2] != 0);
                unsigned long long b3 = __ballot(av[3] != 0);
                if (l == 0) {
                    ulonglong2 p0; p0.x = b0; p0.y = b1;
                    ulonglong2 p1; p1.x = b2; p1.y = b3;
                    *(ulonglong2*)(bprow + (size_t)r * 16) = p0;
                    *(ulonglong2*)(bprow + (size_t)r * 16 + 2) = p1;
                }
                const float esb = S->les[s * 4 + r];
                #pragma unroll
                for (int e = 0; e < 4; ++e) {
                    float x = esb + edv[e];
                    float lk = fmaxf(x, ALPHA * x);
                    float t = __expf(lk - ub[e]);
                    sr[e] += (av[e] != 0) ? t : 0.f;
                }
            }
            __builtin_amdgcn_s_barrier();
        }
        f32x4 s4; s4[0] = sr[0]; s4[1] = sr[1]; s4[2] = sr[2]; s4[3] = sr[3];
        *(f32x4*)&spart[((size_t)(m * 16 + sub)) * 1024 + j0] = s4;
    }
    __threadfence();
    grid.sync();

    // ========== PHASE C: combine + PV MFMA (64 rows) + elu =================
    {
        SC* S = (SC*)smem;
        {   // Ma recompute
            f32x4 ev = *(const f32x4*)&es[m * 1024 + tid * 4];
            float mx = fmaxf(fmaxf(ev[0], ev[1]), fmaxf(ev[2], ev[3]));
            #pragma unroll
            for (int d = 1; d < 64; d <<= 1) mx = fmaxf(mx, __shfl_xor(mx, d));
            if (l == 0) S->red[w] = mx;
        }
        __syncthreads();
        const float Ma = fmaxf(fmaxf(S->red[0], S->red[1]), fmaxf(S->red[2], S->red[3]));
        const int j0 = tid * 4;
        {   // k1b folded: sum 16 partials -> lc/ld/led
            f32x4 Sv = {0.f, 0.f, 0.f, 0.f};
            const float* sp = spart + (size_t)m * 16 * 1024 + j0;
            #pragma unroll
            for (int it = 0; it < 16; ++it) Sv += *(const f32x4*)(sp + it * 1024);
            f32x4 edv4 = *(const f32x4*)&ed[m * 1024 + j0];
            #pragma unroll
            for (int e = 0; e < 4; ++e) {
                float x = Ma + edv4[e];
                float ubv = fmaxf(x, ALPHA * x);
                bool dead = !(Sv[e] > 0.f);
                S->led[j0 + e] = edv4[e];
                S->lc[j0 + e] = dead ? NEG_BIG : ubv;
                S->ld[j0 + e] = dead ? (1.0f / 1024.0f) : 1.0f / Sv[e];
            }
        }
        const int row0 = T0 + w * 16 + cl;
        const float es0 = es[m * 1024 + row0];
        const unsigned long long* bp0 = bits + ((size_t)m * 1024 + row0) * 16;
        f32x4 acc[8];
        const f32x4 vz = {0.f, 0.f, 0.f, 0.f};
        #pragma unroll
        for (int jx = 0; jx < 8; ++jx) acc[jx] = vz;
        const int so = tid >> 1, sh = tid & 1;
        const short* gsrc = whbt + ((size_t)m * 128 + so) * 1024 + sh * 16;
        short* dst0 = &S->Bt[0][so * 40 + sh * 16];
        {
            uint4 r0 = *(const uint4*)gsrc;
            uint4 r1 = *(const uint4*)(gsrc + 8);
            *(uint4*)dst0 = r0;
            *(uint4*)(dst0 + 8) = r1;
        }
        __syncthreads();
        int cur = 0;
        ulonglong2 wa0, wb0;
        wa0.x = wa0.y = wb0.x = wb0.y = 0ull;
        #pragma unroll 2
        for (int kt = 0; kt < 32; ++kt) {
            const int jb = kt * 32 + q * 8;
            if ((kt & 7) == 0) {
                const ulonglong2* q0p = (const ulonglong2*)(bp0 + (kt >> 3) * 4);
                wa0 = q0p[0]; wb0 = q0p[1];
            }
            uint4 n0, n1;
            if (kt < 31) {
                const short* g2 = gsrc + (kt + 1) * 32;
                n0 = *(const uint4*)g2;
                n1 = *(const uint4*)(g2 + 8);
            }
            const f32x4 edA = *(const f32x4*)&S->led[jb], edB = *(const f32x4*)&S->led[jb + 4];
            const f32x4 cA = *(const f32x4*)&S->lc[jb],   cB = *(const f32x4*)&S->lc[jb + 4];
            const f32x4 dA = *(const f32x4*)&S->ld[jb],   dB = *(const f32x4*)&S->ld[jb + 4];
            const int bbase = ((kt & 7) << 3) + (q << 1);
            short8 af0;
            #pragma unroll
            for (int e = 0; e < 8; ++e) {
                const float edvv = (e < 4) ? edA[e] : edB[e - 4];
                const float cv = (e < 4) ? cA[e] : cB[e - 4];
                const float dv = (e < 4) ? dA[e] : dB[e - 4];
                const float x0 = es0 + edvv;
                const float l0 = fmaxf(x0, ALPHA * x0);
                const int bi = bbase + (e >> 2);
                const unsigned long long q0w = (e & 3) == 0 ? wa0.x : (e & 3) == 1 ? wa0.y
                                             : (e & 3) == 2 ? wb0.x : wb0.y;
                const float m0 = ((q0w >> bi) & 1ull) ? l0 : NEG_BIG;
                af0[e] = f2bf(__expf(m0 - cv) * dv);
            }
            #pragma unroll
            for (int nf = 0; nf < 8; ++nf) {
                short8 bf = *(const short8*)&S->Bt[cur][(nf * 16 + cl) * 40 + q * 8];
                acc[nf] = MFMA16(af0, bf, acc[nf]);
            }
            if (kt < 31) {
                short* d2 = &S->Bt[cur ^ 1][so * 40 + sh * 16];
                *(uint4*)d2 = n0;
                *(uint4*)(d2 + 8) = n1;
                cur ^= 1;
            }
            __syncthreads();
        }
        {
            const int rowb = T0 + w * 16 + q * 4;
            #pragma unroll
            for (int nf = 0; nf < 8; ++nf) {
                const int o = nf * 16 + cl;
                #pragma unroll
                for (int r = 0; r < 4; ++r) {
                    const float v = acc[nf][r];
                    const float evv = v > 0.f ? v : (__expf(v) - 1.0f);
                    out[((size_t)m * 1024 + rowb + r) * 128 + o] = evv;
                }
            }
        }
    }
}

// ===========================================================================
// FALLBACK pipeline (R3-style, passing @89.2us) — if coop can't cover 512
// ===========================================================================
__global__ __launch_bounds__(128) void k00_wsd(const float* __restrict__ W,
                                               const float* __restrict__ a,
                                               float* __restrict__ wsv,
                                               float* __restrict__ wdv) {
    int k = blockIdx.x, t = threadIdx.x;
    float v = W[k * 128 + t];
    float ps = v * a[t];
    float pd = v * a[128 + t];
    #pragma unroll
    for (int d = 1; d < 64; d <<= 1) {
        ps += __shfl_xor(ps, d);
        pd += __shfl_xor(pd, d);
    }
    __shared__ float tmp[4];
    if ((t & 63) == 0) { tmp[(t >> 6) * 2] = ps; tmp[(t >> 6) * 2 + 1] = pd; }
    __syncthreads();
    if (t == 0) { wsv[k] = tmp[0] + tmp[2]; wdv[k] = tmp[1] + tmp[3]; }
}

__global__ __launch_bounds__(256) void k0_wh(const float* __restrict__ h,
                                             const float* __restrict__ W,
                                             const float* __restrict__ wsv,
                                             const float* __restrict__ wdv,
                                             short* __restrict__ whbt,
                                             float* __restrict__ es,
                                             float* __restrict__ ed) {
    __shared__ __align__(16) short Wt[128 * 136];
    __shared__ __align__(16) float lws[128], lwd[128];
    const int tid = threadIdx.x;
    const int m = blockIdx.x >> 3, rt = blockIdx.x & 7;
    const int R0 = rt * 128;
    #pragma unroll 4
    for (int i = 0; i < 64; ++i) {
        int idx = i * 256 + tid;
        int k = idx >> 7, o = idx & 127;
        Wt[o * 136 + k] = f2bf(W[idx]);
    }
    if (tid < 128) { lws[tid] = wsv[tid]; lwd[tid] = wdv[tid]; }
    __syncthreads();
    const int w = tid >> 6, l = tid & 63;
    const int q = l >> 4, c = l & 15;
    const int row0 = R0 + w * 32 + c;
    f32x4 acc[2][8];
    const f32x4 vzero = {0.f, 0.f, 0.f, 0.f};
    #pragma unroll
    for (int i = 0; i < 2; ++i)
        #pragma unroll
        for (int j = 0; j < 8; ++j) acc[i][j] = vzero;
    float esp0 = 0.f, edp0 = 0.f, esp1 = 0.f, edp1 = 0.f;
    const float* hrow0 = h + ((size_t)m * 1024 + row0) * 128;
    const float* hrow1 = hrow0 + 16 * 128;
    #pragma unroll
    for (int kk = 0; kk < 128; kk += 32) {
        const int kb = kk + q * 8;
        f32x4 wsA = *(const f32x4*)&lws[kb], wsB = *(const f32x4*)&lws[kb + 4];
        f32x4 wdA = *(const f32x4*)&lwd[kb], wdB = *(const f32x4*)&lwd[kb + 4];
        f32x4 h0a = *(const f32x4*)(hrow0 + kb), h0b = *(const f32x4*)(hrow0 + kb + 4);
        f32x4 h1a = *(const f32x4*)(hrow1 + kb), h1b = *(const f32x4*)(hrow1 + kb + 4);
        short8 af0, af1;
        #pragma unroll
        for (int e = 0; e < 4; ++e) {
            esp0 += h0a[e] * wsA[e] + h0b[e] * wsB[e];
            edp0 += h0a[e] * wdA[e] + h0b[e] * wdB[e];
            esp1 += h1a[e] * wsA[e] + h1b[e] * wsB[e];
            edp1 += h1a[e] * wdA[e] + h1b[e] * wdB[e];
            af0[e] = f2bf(h0a[e]); af0[e + 4] = f2bf(h0b[e]);
            af1[e] = f2bf(h1a[e]); af1[e + 4] = f2bf(h1b[e]);
        }
        #pragma unroll
        for (int nf = 0; nf < 8; ++nf) {
            short8 bf = *(const short8*)&Wt[(nf * 16 + c) * 136 + kb];
            acc[0][nf] = MFMA16(af0, bf, acc[0][nf]);
            acc[1][nf] = MFMA16(af1, bf, acc[1][nf]);
        }
    }
    {
        float v0 = esp0; v0 += __shfl_xor(v0, 16); v0 += __shfl_xor(v0, 32);
        float u0 = edp0; u0 += __shfl_xor(u0, 16); u0 += __shfl_xor(u0, 32);
        float v1 = esp1; v1 += __shfl_xor(v1, 16); v1 += __shfl_xor(v1, 32);
        float u1 = edp1; u1 += __shfl_xor(u1, 16); u1 += __shfl_xor(u1, 32);
        if (q == 0) {
            es[m * 1024 + row0] = v0;       ed[m * 1024 + row0] = u0;
            es[m * 1024 + row0 + 16] = v1;  ed[m * 1024 + row0 + 16] = u1;
        }
    }
    #pragma unroll
    for (int mf = 0; mf < 2; ++mf) {
        const int rowb = R0 + w * 32 + mf * 16 + q * 4;
        #pragma unroll
        for (int nf = 0; nf < 8; ++nf) {
            const int o = nf * 16 + c;
            size_t base = ((size_t)m * 128 + o) * 1024 + rowb;
            #pragma unroll
            for (int r = 0; r < 4; r += 2) {
                unsigned lo = (unsigned short)f2bf(acc[mf][nf][r]);
                unsigned hi = (unsigned short)f2bf(acc[mf][nf][r + 1]);
                *(unsigned*)(whbt + base + r) = lo | (hi << 16);
            }
        }
    }
}

__global__ __launch_bounds__(256) void k0m_max(const float* __restrict__ es,
                                               float* __restrict__ mall) {
    const int m = blockIdx.x, tid = threadIdx.x;
    float4 v = *(const float4*)&es[m * 1024 + tid * 4];
    float mx = fmaxf(fmaxf(v.x, v.y), fmaxf(v.z, v.w));
    #pragma unroll
    for (int d = 1; d < 64; d <<= 1) mx = fmaxf(mx, __shfl_xor(mx, d));
    __shared__ float t[4];
    if ((tid & 63) == 0) t[tid >> 6] = mx;
    __syncthreads();
    if (tid == 0) mall[m] = fmaxf(fmaxf(t[0], t[1]), fmaxf(t[2], t[3]));
}

__global__ __launch_bounds__(256) void k1_stats(const int* __restrict__ adj,
                                                const float* __restrict__ es,
                                                const float* __restrict__ ed,
                                                const float* __restrict__ mall,
                                                unsigned long long* __restrict__ bits,
                                                float* __restrict__ spart) {
    const int b = blockIdx.x;
    const int m = b >> 6, it = b & 63;
    const int tid = threadIdx.x;
    const int w = tid >> 6, l = tid & 63;
    const int j0 = tid * 4;
    const float Ma = mall[m];
    const float4 edv = *(const float4*)&ed[m * 1024 + j0];
    float ub[4];
    #pragma unroll
    for (int e = 0; e < 4; ++e) {
        float x = Ma + ((const float*)&edv)[e];
        ub[e] = fmaxf(x, ALPHA * x);
    }
    const int4* ap = (const int4*)(adj + ((size_t)m * 1024 + it * 16) * 1024) + tid;
    int4 av[16];
    #pragma unroll
    for (int r = 0; r < 16; ++r) av[r] = ap[(size_t)r * 256];
    unsigned long long* bp = bits + ((size_t)m * 1024 + it * 16) * 16 + w * 4;
    #pragma unroll
    for (int r = 0; r < 16; ++r) {
        unsigned long long b0 = __ballot(av[r].x != 0);
        unsigned long long b1 = __ballot(av[r].y != 0);
        unsigned long long b2 = __ballot(av[r].z != 0);
        unsigned long long b3 = __ballot(av[r].w != 0);
        if (l == 0) {
            ulonglong2 p0, p1;
            p0.x = b0; p0.y = b1; p1.x = b2; p1.y = b3;
            *(ulonglong2*)(bp + (size_t)r * 16) = p0;
            *(ulonglong2*)(bp + (size_t)r * 16 + 2) = p1;
        }
    }
    float sr[4] = {0.f, 0.f, 0.f, 0.f};
    const float* ep = es + m * 1024 + it * 16;
    #pragma unroll
    for (int r = 0; r < 16; ++r) {
        const float esb = ep[r];
        #pragma unroll
        for (int e = 0; e < 4; ++e) {
            float x = esb + ((const float*)&edv)[e];
            float lk = fmaxf(x, ALPHA * x);
            float t = __expf(lk - ub[e]);
            sr[e] += ((&av[r].x)[e] != 0) ? t : 0.f;
        }
    }
    float4 s4; s4.x = sr[0]; s4.y = sr[1]; s4.z = sr[2]; s4.w = sr[3];
    *(float4*)&spart[((size_t)(m * 64 + it)) * 1024 + j0] = s4;
}

__global__ __launch_bounds__(256) void k1b_combine(const float* __restrict__ spart,
                                                   const float* __restrict__ ed,
                                                   const float* __restrict__ mall,
                                                   float* __restrict__ cc,
                                                   float* __restrict__ dinv) {
    const int g = blockIdx.x * 256 + threadIdx.x;
    const int m = g >> 10, j = g & 1023;
    const float* sp = spart + (size_t)m * 64 * 1024 + j;
    float S = 0.f;
    #pragma unroll
    for (int it = 0; it < 64; ++it) S += sp[it * 1024];
    float x = mall[m] + ed[g];
    float ub = fmaxf(x, ALPHA * x);
    bool dead = !(S > 0.f);
    cc[g] = dead ? NEG_BIG : ub;
    dinv[g] = dead ? (1.0f / 1024.0f) : 1.0f / S;
}

__global__ __launch_bounds__(256) void k2_pv(const unsigned long long* __restrict__ bits,
                                             const short* __restrict__ whbt,
                                             const float* __restrict__ es,
                                             const float* __restrict__ ed,
                                             const float* __restrict__ cc,
                                             const float* __restrict__ dinv,
                                             float* __restrict__ out) {
    __shared__ __align__(16) short Bt[2][128 * 40];
    __shared__ __align__(16) float led[1024], lc[1024], ld[1024];
    const int tid = threadIdx.x;
    const int m = blockIdx.x >> 3, rt = blockIdx.x & 7;
    const int R0 = rt * 128;
    for (int i = tid; i < 1024; i += 256) {
        led[i] = ed[m * 1024 + i];
        lc[i] = cc[m * 1024 + i];
        ld[i] = dinv[m * 1024 + i];
    }
    const int w = tid >> 6, l = tid & 63, q = l >> 4, cl = l & 15;
    const int row0 = R0 + w * 32 + cl;
    const float es0 = es[m * 1024 + row0];
    const float es1 = es[m * 1024 + row0 + 16];
    const unsigned long long* bp0 = bits + ((size_t)m * 1024 + row0) * 16;
    const unsigned long long* bp1 = bp0 + 16 * 16;
    f32x4 acc[2][8];
    const f32x4 vzero = {0.f, 0.f, 0.f, 0.f};
    #pragma unroll
    for (int i = 0; i < 2; ++i)
        #pragma unroll
        for (int jx = 0; jx < 8; ++jx) acc[i][jx] = vzero;
    const int so = tid >> 1, sh = tid & 1;
    const short* gsrc = whbt + ((size_t)m * 128 + so) * 1024 + sh * 16;
    short* dst0 = &Bt[0][so * 40 + sh * 16];
    {
        uint4 r0 = *(const uint4*)gsrc;
        uint4 r1 = *(const uint4*)(gsrc + 8);
        *(uint4*)dst0 = r0;
        *(uint4*)(dst0 + 8) = r1;
    }
    __syncthreads();
    int cur = 0;
    ulonglong2 wa0, wb0, wa1, wb1;
    wa0.x = wa0.y = wb0.x = wb0.y = 0ull;
    wa1.x = wa1.y = wb1.x = wb1.y = 0ull;
    #pragma unroll 2
    for (int kt = 0; kt < 32; ++kt) {
        const int jb = kt * 32 + q * 8;
        if ((kt & 7) == 0) {
            const ulonglong2* q0 = (const ulonglong2*)(bp0 + (kt >> 3) * 4);
            wa0 = q0[0]; wb0 = q0[1];
            const ulonglong2* q1 = (const ulonglong2*)(bp1 + (kt >> 3) * 4);
            wa1 = q1[0]; wb1 = q1[1];
        }
        uint4 n0, n1;
        if (kt < 31) {
            const short* g2 = gsrc + (kt + 1) * 32;
            n0 = *(const uint4*)g2;
            n1 = *(const uint4*)(g2 + 8);
        }
        const f32x4 edA = *(const f32x4*)&led[jb], edB = *(const f32x4*)&led[jb + 4];
        const f32x4 cA = *(const f32x4*)&lc[jb],   cB = *(const f32x4*)&lc[jb + 4];
        const f32x4 dA = *(const f32x4*)&ld[jb],   dB = *(const f32x4*)&ld[jb + 4];
        const int bbase = ((kt & 7) << 3) + (q << 1);
        short8 af0, af1;
        #pragma unroll
        for (int e = 0; e < 8; ++e) {
            const float edv = (e < 4) ? edA[e] : edB[e - 4];
            const float cv = (e < 4) ? cA[e] : cB[e - 4];
            const float dv = (e < 4) ? dA[e] : dB[e - 4];
            const float x0 = es0 + edv, x1 = es1 + edv;
            const float l0 = fmaxf(x0, ALPHA * x0), l1 = fmaxf(x1, ALPHA * x1);
            const int bi = bbase + (e >> 2);
            const unsigned long long q0w = (e & 3) == 0 ? wa0.x : (e & 3) == 1 ? wa0.y
                                         : (e & 3) == 2 ? wb0.x : wb0.y;
            const unsigned long long q1w = (e & 3) == 0 ? wa1.x : (e & 3) == 1 ? wa1.y
                                         : (e & 3) == 2 ? wb1.x : wb1.y;
            const float m0 = ((q0w >> bi) & 1ull) ? l0 : NEG_BIG;
            const float m1 = ((q1w >> bi) & 1ull) ? l1 : NEG_BIG;
            af0[e] = f2bf(__expf(m0 - cv) * dv);
            af1[e] = f2bf(__expf(m1 - cv) * dv);
        }
        const short* bb = &Bt[cur][0];
        #pragma unroll
        for (int nf = 0; nf < 8; ++nf) {
            short8 bf = *(const short8*)&bb[(nf * 16 + cl) * 40 + q * 8];
            acc[0][nf] = MFMA16(af0, bf, acc[0][nf]);
            acc[1][nf] = MFMA16(af1, bf, acc[1][nf]);
        }
        if (kt < 31) {
            short* d2 = &Bt[cur ^ 1][so * 40 + sh * 16];
            *(uint4*)d2 = n0;
            *(uint4*)(d2 + 8) = n1;
            cur ^= 1;
        }
        __syncthreads();
    }
    #pragma unroll
    for (int mf = 0; mf < 2; ++mf) {
        const int rowb = R0 + w * 32 + mf * 16 + q * 4;
        #pragma unroll
        for (int nf = 0; nf < 8; ++nf) {
            const int o = nf * 16 + cl;
            #pragma unroll
            for (int r = 0; r < 4; ++r) {
                const float v = acc[mf][nf][r];
                const float evv = v > 0.f ? v : (__expf(v) - 1.0f);
                out[((size_t)m * 1024 + rowb + r) * 128 + o] = evv;
            }
        }
    }
}

// ---------------------------------------------------------------------------
extern "C" void kernel_launch(void* const* d_in, const int* in_sizes, int n_in,
                              void* d_out, int out_size, void* d_ws, size_t ws_size,
                              hipStream_t stream) {
    const float* h = (const float*)d_in[0];
    const int* adj = (const int*)d_in[1];
    const float* W = (const float*)d_in[2];
    const float* a = (const float*)d_in[3];
    float* out = (float*)d_out;

    char* p = (char*)d_ws;
    auto alloc = [&](size_t bytes) -> char* {
        char* r = p;
        p += (bytes + 255) & ~(size_t)255;
        return r;
    };
    short* whbt = (short*)alloc((size_t)32 * 128 * 1024 * 2);                          // 8 MB
    float* es = (float*)alloc((size_t)32 * 1024 * 4);
    float* ed = (float*)alloc((size_t)32 * 1024 * 4);
    float* wsv = (float*)alloc(128 * 4);
    float* wdv = (float*)alloc(128 * 4);
    float* mall = (float*)alloc(32 * 4);
    unsigned long long* bits = (unsigned long long*)alloc((size_t)32 * 1024 * 16 * 8); // 4 MB
    float* spart = (float*)alloc((size_t)32 * 64 * 1024 * 4);                          // 8 MB (max of both paths)
    float* cc = (float*)alloc((size_t)32 * 1024 * 4);
    float* dinv = (float*)alloc((size_t)32 * 1024 * 4);

    // Deterministic, capture-safe decision: can 512 coop blocks co-reside?
    int maxBlk = 0;
    hipError_t oe = hipOccupancyMaxActiveBlocksPerMultiprocessor(
        &maxBlk, (const void*)gat_mega, 256, 0);
    int numCU = 0;
    hipError_t ae = hipDeviceGetAttribute(&numCU, hipDeviceAttributeMultiprocessorCount, 0);
    bool useCoop = (oe == hipSuccess) && (ae == hipSuccess) &&
                   ((long long)maxBlk * numCU >= 512);

    if (useCoop) {
        void* kargs[] = { (void*)&h, (void*)&adj, (void*)&W, (void*)&a,
                          (void*)&whbt, (void*)&es, (void*)&ed, (void*)&bits,
                          (void*)&spart, (void*)&out };
        hipLaunchCooperativeKernel(reinterpret_cast<void*>(gat_mega), dim3(512), dim3(256),
                                   kargs, 0, stream);
    } else {
        k00_wsd<<<128, 128, 0, stream>>>(W, a, wsv, wdv);
        k0_wh<<<256, 256, 0, stream>>>(h, W, wsv, wdv, whbt, es, ed);
        k0m_max<<<32, 256, 0, stream>>>(es, mall);
        k1_stats<<<2048, 256, 0, stream>>>(adj, es, ed, mall, bits, spart);
        k1b_combine<<<128, 256, 0, stream>>>(spart, ed, mall, cc, dinv);
        k2_pv<<<256, 256, 0, stream>>>(bits, whbt, es, ed, cc, dinv, out);
    }
}